// Round 2
// baseline (216.732 us; speedup 1.0000x reference)
//
#include <hip/hip_runtime.h>

// AdaptiveDecayMemory: out = ((Q K^T * scale) ∘ W_decay) V Wo^T * out_scale
// B=4, T=2048, D=1024.  bf16 MFMA, fp32 accum.
// Main GEMMs: 256x256 8-phase pipelined template (T2 swizzle + T3/T4 counted
// vmcnt + T5 setprio).  VT GEMM: 128x128 m97-structure (better fill).

using u16 = unsigned short;
typedef __bf16 bf16x8 __attribute__((ext_vector_type(8)));
typedef float f32x4 __attribute__((ext_vector_type(4)));

__device__ inline u16 f2bf(float f) {
  unsigned u = __builtin_bit_cast(unsigned, f);
  unsigned r = (u + 0x7FFFu + ((u >> 16) & 1u)) >> 16;   // RNE
  return (u16)r;
}

__device__ inline void gload16(const u16* g, u16* l) {
  __builtin_amdgcn_global_load_lds(
      (const __attribute__((address_space(1))) void*)g,
      (__attribute__((address_space(3))) void*)l, 16, 0, 0);
}

// ---------- fused x cast (fp32->bf16) + decay logit GEMV ----------
// one block = one row of x (1024 floats)
__global__ __launch_bounds__(256) void xcast_decay(const float* __restrict__ x,
    u16* __restrict__ Xbf, const float* __restrict__ Wd,
    const float* __restrict__ bd, float* __restrict__ ldec) {
  int row = blockIdx.x;
  int t = threadIdx.x;
  float4 f = reinterpret_cast<const float4*>(x + (size_t)row * 1024)[t];
  float4 g = reinterpret_cast<const float4*>(Wd)[t];
  ushort4 o;
  o.x = f2bf(f.x); o.y = f2bf(f.y); o.z = f2bf(f.z); o.w = f2bf(f.w);
  reinterpret_cast<ushort4*>(Xbf + (size_t)row * 1024)[t] = o;
  float s = f.x * g.x + f.y * g.y + f.z * g.z + f.w * g.w;
  #pragma unroll
  for (int off = 32; off > 0; off >>= 1) s += __shfl_xor(s, off);
  __shared__ float red[4];
  if ((t & 63) == 0) red[t >> 6] = s;
  __syncthreads();
  if (t == 0) {
    float tot = red[0] + red[1] + red[2] + red[3];
    float dec = 1.f / (1.f + expf(-(tot + bd[0])));
    ldec[row] = logf(dec + 1e-8f);
  }
}

// ---------- weight cast: [Wq;Wk;Wv;Wo] -> Wall (4 x 1M bf16) ----------
__global__ __launch_bounds__(256) void wcast(const float* __restrict__ Wq,
    const float* __restrict__ Wk, const float* __restrict__ Wv,
    const float* __restrict__ Wo, u16* __restrict__ Wall) {
  int b = blockIdx.x;
  int m = b >> 10;
  const float* src = (m == 0) ? Wq : (m == 1) ? Wk : (m == 2) ? Wv : Wo;
  int i = ((b & 1023) * 256 + threadIdx.x) * 4;
  float4 f = *reinterpret_cast<const float4*>(src + i);
  ushort4 o;
  o.x = f2bf(f.x); o.y = f2bf(f.y); o.z = f2bf(f.z); o.w = f2bf(f.w);
  *reinterpret_cast<ushort4*>(Wall + (size_t)m * 1048576 + i) = o;
}

// ---------- 128x128 m97-structure GEMM (kept for VT) ----------
#define BM 128
#define BN 128
#define BKK 64

template <int EPI>
__global__ __launch_bounds__(256, 2)
void gemm_bt(const u16* __restrict__ Ab, const u16* __restrict__ Bb,
             void* __restrict__ Cv, int lda, int ldb, int ldc, int K,
             int tiles_n, int diag, const float* __restrict__ ldec,
             const float* __restrict__ scale_ptr,
             long long abs_, long long bbs_, long long cbs_, int ld_stride) {
  __shared__ __align__(16) u16 lsA[BM * BKK];
  __shared__ __align__(16) u16 lsB[BN * BKK];

  const int batch = blockIdx.y;
  const u16* A = Ab + (size_t)batch * abs_;
  const u16* B = Bb + (size_t)batch * bbs_;

  const int it = blockIdx.x / tiles_n;
  const int jt = blockIdx.x % tiles_n;
  if (EPI == 1 && jt < it) return;
  const int m0 = it * BM, n0 = jt * BN;

  const int tid = threadIdx.x;
  const int lane = tid & 63;
  const int w = tid >> 6;
  const int wm = (w >> 1) * 64, wn = (w & 1) * 64;
  const int l15 = lane & 15, lhi = lane >> 4;
  const int srow = lane >> 3;
  const int schunk = (lane & 7) ^ srow;

  f32x4 acc[4][4];
  #pragma unroll
  for (int i = 0; i < 4; ++i)
    #pragma unroll
    for (int j = 0; j < 4; ++j) acc[i][j] = (f32x4)0.f;

  const int kt0 = diag ? it * (BM / BKK) : 0;
  const int nkt = K / BKK;

  for (int kt = kt0; kt < nkt; ++kt) {
    const int k0 = kt * BKK;
    __syncthreads();
    #pragma unroll
    for (int is = 0; is < 4; ++is) {
      int r = (is * 4 + w) * 8 + srow;
      gload16(A + (size_t)(m0 + r) * lda + (k0 + schunk * 8), &lsA[(is * 4 + w) * 512]);
    }
    #pragma unroll
    for (int is = 0; is < 4; ++is) {
      int r = (is * 4 + w) * 8 + srow;
      gload16(B + (size_t)(n0 + r) * ldb + (k0 + schunk * 8), &lsB[(is * 4 + w) * 512]);
    }
    __syncthreads();
    #pragma unroll
    for (int kk = 0; kk < 2; ++kk) {
      bf16x8 af[4], bv[4];
      #pragma unroll
      for (int mi = 0; mi < 4; ++mi) {
        int r = wm + mi * 16 + l15;
        int s = (kk * 4 + lhi) ^ (r & 7);
        af[mi] = *reinterpret_cast<const bf16x8*>(&lsA[r * 64 + s * 8]);
      }
      #pragma unroll
      for (int ni = 0; ni < 4; ++ni) {
        int r = wn + ni * 16 + l15;
        int s = (kk * 4 + lhi) ^ (r & 7);
        bv[ni] = *reinterpret_cast<const bf16x8*>(&lsB[r * 64 + s * 8]);
      }
      #pragma unroll
      for (int mi = 0; mi < 4; ++mi)
        #pragma unroll
        for (int ni = 0; ni < 4; ++ni)
          acc[mi][ni] = __builtin_amdgcn_mfma_f32_16x16x32_bf16(af[mi], bv[ni], acc[mi][ni], 0, 0, 0);
    }
  }

  if (EPI == 0) {
    u16* C = (u16*)Cv + (size_t)batch * cbs_;
    #pragma unroll
    for (int mi = 0; mi < 4; ++mi)
      #pragma unroll
      for (int q = 0; q < 4; ++q) {
        int row = m0 + wm + mi * 16 + lhi * 4 + q;
        u16* crow = C + (size_t)row * ldc + n0 + wn + l15;
        #pragma unroll
        for (int ni = 0; ni < 4; ++ni) crow[ni * 16] = f2bf(acc[mi][ni][q]);
      }
  } else if (EPI == 1) {
    u16* C = (u16*)Cv + (size_t)batch * cbs_;
    const float* ldb_ = ldec + (size_t)batch * ld_stride;
    float ldv[4];
    #pragma unroll
    for (int ni = 0; ni < 4; ++ni) ldv[ni] = ldb_[n0 + wn + ni * 16 + l15];
    const float sc = 0.03125f;
    #pragma unroll
    for (int mi = 0; mi < 4; ++mi)
      #pragma unroll
      for (int q = 0; q < 4; ++q) {
        int row = m0 + wm + mi * 16 + lhi * 4 + q;
        u16* crow = C + (size_t)row * ldc + n0 + wn + l15;
        #pragma unroll
        for (int ni = 0; ni < 4; ++ni) {
          int col = n0 + wn + ni * 16 + l15;
          int d = col - row;
          float wgt = (d > 0) ? expf(ldv[ni] * (float)(d - 1)) : 0.f;
          crow[ni * 16] = f2bf(acc[mi][ni][q] * sc * wgt);
        }
      }
  } else {
    float* C = (float*)Cv + (size_t)batch * cbs_;
    const float sc = scale_ptr[0];
    #pragma unroll
    for (int mi = 0; mi < 4; ++mi)
      #pragma unroll
      for (int q = 0; q < 4; ++q) {
        int row = m0 + wm + mi * 16 + lhi * 4 + q;
        float* crow = C + (size_t)row * ldc + n0 + wn + l15;
        #pragma unroll
        for (int ni = 0; ni < 4; ++ni) crow[ni * 16] = acc[mi][ni][q] * sc;
      }
  }
}

// ---------- 256x256 8-phase pipelined GEMM ----------
// 8 waves (2M x 4N), per-wave 128x64 out, BK=64, 2-deep LDS dbuf (2x64KB).
// Phase p consumes quadrant (qm,qn) in order (0,0),(0,1),(1,1),(1,0).
// Staging (16KB/phase, per-region staggered so writes only hit regions whose
// last reader was fenced one barrier earlier):
//   p0: B-qn0 strips of tile t+1 -> other buf
//   p1: A-q0 of tile t+2 -> this buf   (A-q0 read at p0)
//   p2: B-qn1 of tile t+2 -> this buf  (B-qn1 read at p1)
//   p3: A-q1 of tile t+2 -> this buf   (A-q1 read at p2)
// vmcnt(6) once per K-tile (3 half-stages in flight) at p3, before barrier.

#define SBAR0() __builtin_amdgcn_sched_barrier(0)

template <int EPI>
__global__ __launch_bounds__(512, 2)
void gemm256(const u16* __restrict__ Ab, const u16* __restrict__ Bb,
             void* __restrict__ Cv, int lda, int ldb, int ldc, int K,
             int tiles_n, int diag, const float* __restrict__ ldec,
             const float* __restrict__ scale_ptr,
             long long abs_, long long bbs_, long long cbs_, int ld_stride) {
  __shared__ __align__(16) u16 lds2[65536];   // 128 KiB: 2 bufs x (A 32K | B 32K)

  const int batch = blockIdx.y;
  const u16* A = Ab + (size_t)batch * abs_;
  const u16* B = Bb + (size_t)batch * bbs_;

  const int it = blockIdx.x / tiles_n;
  const int jt = blockIdx.x % tiles_n;
  if (EPI == 1 && jt < it) return;
  const int m0 = it * 256, n0 = jt * 256;

  const int tid = threadIdx.x;
  const int lane = tid & 63;
  const int w = tid >> 6;                // 0..7
  const int wm = w >> 2, wn = w & 3;     // wave tile 2x4
  const int l15 = lane & 15, lhi = lane >> 4;
  const int lr8 = lane >> 3;             // row within an 8-row unit
  const int schunk = (lane & 7) ^ lr8;   // pre-swizzled source chunk

  const int kt0 = diag ? it * 4 : 0;
  const int nkt = K / 64;
  const int span = nkt - kt0;

  f32x4 acc[8][4];
  #pragma unroll
  for (int i = 0; i < 8; ++i)
    #pragma unroll
    for (int j = 0; j < 4; ++j) acc[i][j] = (f32x4)0.f;

  // ---- staging: each call = 2 gload_lds/thread = 16KB ----
  auto stageA = [&](int qm, int kt, int buf) {
    #pragma unroll
    for (int li = 0; li < 2; ++li) {
      int u = li * 8 + w;
      int h = u >> 3;
      int rl = qm * 64 + (u & 7) * 8;
      gload16(A + (size_t)(m0 + h * 128 + rl + lr8) * lda + (size_t)(kt * 64 + schunk * 8),
              &lds2[buf * 32768 + h * 8192 + rl * 64]);
    }
  };
  auto stageB = [&](int qn, int kt, int buf) {
    #pragma unroll
    for (int li = 0; li < 2; ++li) {
      int u = li * 8 + w;
      int h = u >> 3, sub = (u >> 2) & 1;
      int rl = qn * 32 + sub * 64 + (u & 3) * 8;
      gload16(B + (size_t)(n0 + h * 128 + rl + lr8) * ldb + (size_t)(kt * 64 + schunk * 8),
              &lds2[buf * 32768 + 16384 + h * 8192 + rl * 64]);
    }
  };

  bf16x8 af[4][2], bv[2][2];
  auto readA = [&](int qm, int buf) {
    const u16* base = &lds2[buf * 32768 + wm * 8192];
    #pragma unroll
    for (int mi = 0; mi < 4; ++mi) {
      int r = qm * 64 + mi * 16 + l15;
      #pragma unroll
      for (int kk = 0; kk < 2; ++kk) {
        int s = (kk * 4 + lhi) ^ (r & 7);
        af[mi][kk] = *reinterpret_cast<const bf16x8*>(&base[r * 64 + s * 8]);
      }
    }
  };
  auto readB = [&](int qn, int buf) {
    const u16* base = &lds2[buf * 32768 + 16384 + (wn >> 1) * 8192];
    #pragma unroll
    for (int ni = 0; ni < 2; ++ni) {
      int r = (wn & 1) * 64 + qn * 32 + ni * 16 + l15;
      #pragma unroll
      for (int kk = 0; kk < 2; ++kk) {
        int s = (kk * 4 + lhi) ^ (r & 7);
        bv[ni][kk] = *reinterpret_cast<const bf16x8*>(&base[r * 64 + s * 8]);
      }
    }
  };
  auto mmaq = [&](int qm, int qn) {
    #pragma unroll
    for (int kk = 0; kk < 2; ++kk)
      #pragma unroll
      for (int mi = 0; mi < 4; ++mi)
        #pragma unroll
        for (int ni = 0; ni < 2; ++ni)
          acc[qm * 4 + mi][qn * 2 + ni] = __builtin_amdgcn_mfma_f32_16x16x32_bf16(
              af[mi][kk], bv[ni][kk], acc[qm * 4 + mi][qn * 2 + ni], 0, 0, 0);
  };

  // ---- prologue: tile0 fully + tile1 {A-q0, B-qn1, A-q1} ----
  {
    int k0 = kt0;
    int k1 = kt0 + (1 < span ? 1 : 0);
    stageA(0, k0, 0); stageB(0, k0, 0); stageA(1, k0, 0); stageB(1, k0, 0);
    stageA(0, k1, 1); stageB(1, k1, 1); stageA(1, k1, 1);
  }
  asm volatile("s_waitcnt vmcnt(6)" ::: "memory");
  __builtin_amdgcn_s_barrier();
  SBAR0();

  for (int t = 0; t < span; ++t) {
    const int buf = t & 1, nb = buf ^ 1;
    int t1 = t + 1; if (t1 >= span) t1 -= span;
    int t2 = t + 2; if (t2 >= span) t2 -= span;
    const int kt1 = kt0 + t1, kt2 = kt0 + t2;

    // ---- phase 0: quadrant (0,0) ----
    readA(0, buf); readB(0, buf);
    stageB(0, kt1, nb);
    SBAR0(); __builtin_amdgcn_s_barrier();
    asm volatile("s_waitcnt lgkmcnt(0)" ::: "memory"); SBAR0();
    __builtin_amdgcn_s_setprio(1); mmaq(0, 0); __builtin_amdgcn_s_setprio(0);
    SBAR0(); __builtin_amdgcn_s_barrier(); SBAR0();

    // ---- phase 1: quadrant (0,1) ----
    readB(1, buf);
    stageA(0, kt2, buf);
    SBAR0(); __builtin_amdgcn_s_barrier();
    asm volatile("s_waitcnt lgkmcnt(0)" ::: "memory"); SBAR0();
    __builtin_amdgcn_s_setprio(1); mmaq(0, 1); __builtin_amdgcn_s_setprio(0);
    SBAR0(); __builtin_amdgcn_s_barrier(); SBAR0();

    // ---- phase 2: quadrant (1,1) ----
    readA(1, buf);
    stageB(1, kt2, buf);
    SBAR0(); __builtin_amdgcn_s_barrier();
    asm volatile("s_waitcnt lgkmcnt(0)" ::: "memory"); SBAR0();
    __builtin_amdgcn_s_setprio(1); mmaq(1, 1); __builtin_amdgcn_s_setprio(0);
    SBAR0(); __builtin_amdgcn_s_barrier(); SBAR0();

    // ---- phase 3: quadrant (1,0) ----
    readB(0, buf);
    stageA(1, kt2, buf);
    SBAR0(); __builtin_amdgcn_s_barrier();
    asm volatile("s_waitcnt lgkmcnt(0)" ::: "memory"); SBAR0();
    __builtin_amdgcn_s_setprio(1); mmaq(1, 0); __builtin_amdgcn_s_setprio(0);
    asm volatile("s_waitcnt vmcnt(6)" ::: "memory");
    SBAR0(); __builtin_amdgcn_s_barrier(); SBAR0();
  }

  // ---- epilogue ----
  if (EPI == 0) {
    u16* C = (u16*)Cv + (size_t)batch * cbs_;
    #pragma unroll
    for (int a = 0; a < 8; ++a) {
      int ro = (a >> 2) * 64 + (a & 3) * 16;
      #pragma unroll
      for (int q = 0; q < 4; ++q) {
        int row = m0 + wm * 128 + ro + lhi * 4 + q;
        u16* crow = C + (size_t)row * ldc + n0 + wn * 64 + l15;
        #pragma unroll
        for (int ni = 0; ni < 4; ++ni) crow[ni * 16] = f2bf(acc[a][ni][q]);
      }
    }
  } else if (EPI == 1) {
    u16* C = (u16*)Cv + (size_t)batch * cbs_;
    const float* ldp = ldec + (size_t)batch * ld_stride;
    float ldv[4];
    #pragma unroll
    for (int ni = 0; ni < 4; ++ni) ldv[ni] = ldp[n0 + wn * 64 + ni * 16 + l15];
    const float sc = 0.03125f;   // 1/sqrt(1024)
    #pragma unroll
    for (int a = 0; a < 8; ++a) {
      int ro = (a >> 2) * 64 + (a & 3) * 16;
      #pragma unroll
      for (int q = 0; q < 4; ++q) {
        int row = m0 + wm * 128 + ro + lhi * 4 + q;
        u16* crow = C + (size_t)row * ldc + n0 + wn * 64 + l15;
        #pragma unroll
        for (int ni = 0; ni < 4; ++ni) {
          int col = n0 + wn * 64 + ni * 16 + l15;
          int d = col - row;
          float wgt = (d > 0) ? expf(ldv[ni] * (float)(d - 1)) : 0.f;
          crow[ni * 16] = f2bf(acc[a][ni][q] * sc * wgt);
        }
      }
    }
  } else {
    float* C = (float*)Cv + (size_t)batch * cbs_;
    const float sc = scale_ptr[0];
    #pragma unroll
    for (int a = 0; a < 8; ++a) {
      int ro = (a >> 2) * 64 + (a & 3) * 16;
      #pragma unroll
      for (int q = 0; q < 4; ++q) {
        int row = m0 + wm * 128 + ro + lhi * 4 + q;
        float* crow = C + (size_t)row * ldc + n0 + wn * 64 + l15;
        #pragma unroll
        for (int ni = 0; ni < 4; ++ni) crow[ni * 16] = acc[a][ni][q] * sc;
      }
    }
  }
  asm volatile("s_waitcnt vmcnt(0)" ::: "memory");  // drain tail prefetches
}

extern "C" void kernel_launch(void* const* d_in, const int* in_sizes, int n_in,
                              void* d_out, int out_size, void* d_ws, size_t ws_size,
                              hipStream_t stream) {
  const float* x   = (const float*)d_in[0];
  const float* Wq  = (const float*)d_in[1];
  const float* Wk  = (const float*)d_in[2];
  const float* Wv  = (const float*)d_in[3];
  const float* Wo  = (const float*)d_in[4];
  const float* Wd  = (const float*)d_in[5];
  const float* bd  = (const float*)d_in[6];
  const float* osc = (const float*)d_in[7];
  float* out = (float*)d_out;

  char* ws = (char*)d_ws;
  size_t off = 0;
  u16* Xbf  = (u16*)(ws + off); off += (size_t)8192 * 1024 * 2;     // 16.78 MB
  u16* Wall = (u16*)(ws + off); off += (size_t)4096 * 1024 * 2;     //  8.39 MB [Wq;Wk;Wv;Wo]
  u16* VT   = (u16*)(ws + off); off += (size_t)1024 * 8192 * 2;     // 16.78 MB
  u16* S    = (u16*)(ws + off); off += (size_t)4 * 2048 * 2048 * 2; // 33.55 MB
  float* ldec = (float*)(ws + off); off += (size_t)8192 * 4;
  u16* QK   = (u16*)(ws + off); off += (size_t)8192 * 2048 * 2;     // 33.55 MB
  u16* R    = QK;  // alias: QK dead once S built

  u16* Wqk = Wall;                  // rows 0-2047: [Wq; Wk]
  u16* Wvb = Wall + 2 * 1048576;
  u16* Wob = Wall + 3 * 1048576;

  // 1) casts + decay
  xcast_decay<<<8192, 256, 0, stream>>>(x, Xbf, Wd, bd, ldec);
  wcast<<<4096, 256, 0, stream>>>(Wq, Wk, Wv, Wo, Wall);

  // 2) QK = Xbf @ Wqk^T  [8192 x 2048]
  gemm256<0><<<dim3(32 * 8, 1), 512, 0, stream>>>(
      Xbf, Wqk, QK, 1024, 1024, 2048, 1024, 8, 0, nullptr, nullptr, 0, 0, 0, 0);

  // 3) VT = Wvb @ Xbf^T  [1024 x 8192]
  gemm_bt<0><<<dim3(8 * 64, 1), 256, 0, stream>>>(
      Wvb, Xbf, VT, 1024, 1024, 8192, 1024, 64, 0, nullptr, nullptr, 0, 0, 0, 0);

  // 4) S_b = (Q_b K_b^T /32) ∘ weights -> bf16, upper-tri tiles
  gemm256<1><<<dim3(8 * 8, 4), 512, 0, stream>>>(
      QK, QK + 1024, S, 2048, 2048, 2048, 1024, 8, 0, ldec, nullptr,
      4194304LL, 4194304LL, 4194304LL, 2048);

  // 5) R_b = S_b @ V_b  [2048 x 1024], K-loop from diagonal
  gemm256<0><<<dim3(8 * 4, 4), 512, 0, stream>>>(
      S, VT, R, 2048, 8192, 1024, 2048, 4, 1, nullptr, nullptr,
      4194304LL, 2048LL, 2097152LL, 0);

  // 6) out = R @ Wo^T * out_scale  [8192 x 1024] fp32
  gemm256<2><<<dim3(32 * 4, 1), 512, 0, stream>>>(
      R, Wob, out, 1024, 1024, 1024, 1024, 4, 0, nullptr, osc, 0, 0, 0, 0);
}

// Round 3
// 194.502 us; speedup vs baseline: 1.1143x; 1.1143x over previous
//
#include <hip/hip_runtime.h>

// AdaptiveDecayMemory: out = ((Q K^T * scale) ∘ W_decay) V Wo^T * out_scale
// B=4, T=2048, D=1024.  bf16 MFMA, fp32 accum.
// gemm256  : 256x256, 4-phase/K-tile pipelined (counted vmcnt, setprio),
//            NO sched_barrier / explicit lgkmcnt (m141 lesson).
// gemm256n : 256x128, minimum-2-phase (T3 catalog recipe), for exact 256-block
//            fill on the smaller GEMMs (VT, R, out).

using u16 = unsigned short;
typedef __bf16 bf16x8 __attribute__((ext_vector_type(8)));
typedef float f32x4 __attribute__((ext_vector_type(4)));

__device__ inline u16 f2bf(float f) {
  unsigned u = __builtin_bit_cast(unsigned, f);
  unsigned r = (u + 0x7FFFu + ((u >> 16) & 1u)) >> 16;   // RNE
  return (u16)r;
}

__device__ inline void gload16(const u16* g, u16* l) {
  __builtin_amdgcn_global_load_lds(
      (const __attribute__((address_space(1))) void*)g,
      (__attribute__((address_space(3))) void*)l, 16, 0, 0);
}

// ---------- fused x cast (fp32->bf16) + decay logit GEMV ----------
__global__ __launch_bounds__(256) void xcast_decay(const float* __restrict__ x,
    u16* __restrict__ Xbf, const float* __restrict__ Wd,
    const float* __restrict__ bd, float* __restrict__ ldec) {
  int row = blockIdx.x;
  int t = threadIdx.x;
  float4 f = reinterpret_cast<const float4*>(x + (size_t)row * 1024)[t];
  float4 g = reinterpret_cast<const float4*>(Wd)[t];
  ushort4 o;
  o.x = f2bf(f.x); o.y = f2bf(f.y); o.z = f2bf(f.z); o.w = f2bf(f.w);
  reinterpret_cast<ushort4*>(Xbf + (size_t)row * 1024)[t] = o;
  float s = f.x * g.x + f.y * g.y + f.z * g.z + f.w * g.w;
  #pragma unroll
  for (int off = 32; off > 0; off >>= 1) s += __shfl_xor(s, off);
  __shared__ float red[4];
  if ((t & 63) == 0) red[t >> 6] = s;
  __syncthreads();
  if (t == 0) {
    float tot = red[0] + red[1] + red[2] + red[3];
    float dec = 1.f / (1.f + expf(-(tot + bd[0])));
    ldec[row] = logf(dec + 1e-8f);
  }
}

// ---------- weight cast: [Wq;Wk;Wv;Wo] -> Wall ----------
__global__ __launch_bounds__(256) void wcast(const float* __restrict__ Wq,
    const float* __restrict__ Wk, const float* __restrict__ Wv,
    const float* __restrict__ Wo, u16* __restrict__ Wall) {
  int b = blockIdx.x;
  int m = b >> 10;
  const float* src = (m == 0) ? Wq : (m == 1) ? Wk : (m == 2) ? Wv : Wo;
  int i = ((b & 1023) * 256 + threadIdx.x) * 4;
  float4 f = *reinterpret_cast<const float4*>(src + i);
  ushort4 o;
  o.x = f2bf(f.x); o.y = f2bf(f.y); o.z = f2bf(f.z); o.w = f2bf(f.w);
  *reinterpret_cast<ushort4*>(Wall + (size_t)m * 1048576 + i) = o;
}

// ---------- 256x256 4-phase pipelined GEMM ----------
// 8 waves (2M x 4N), per-wave 128x64 out, BK=64, 2-deep LDS dbuf (2x64KB).
// Phase p consumes quadrant (qm,qn) in order (0,0),(0,1),(1,1),(1,0).
// Region-staggered staging (overwrite only regions whose last reader was
// fenced one barrier earlier); vmcnt(6) once per K-tile at p3.
template <int EPI>
__global__ __launch_bounds__(512, 2)
void gemm256(const u16* __restrict__ Ab, const u16* __restrict__ Bb,
             void* __restrict__ Cv, int lda, int ldb, int ldc, int K,
             int tiles_n, const float* __restrict__ ldec,
             long long abs_, long long bbs_, long long cbs_, int ld_stride) {
  __shared__ __align__(16) u16 lds2[65536];   // 128 KiB

  const int batch = blockIdx.y;
  const u16* A = Ab + (size_t)batch * abs_;
  const u16* B = Bb + (size_t)batch * bbs_;

  const int it = blockIdx.x / tiles_n;
  const int jt = blockIdx.x % tiles_n;
  if (EPI == 1 && jt < it) return;
  const int m0 = it * 256, n0 = jt * 256;

  const int tid = threadIdx.x;
  const int lane = tid & 63;
  const int w = tid >> 6;                // 0..7
  const int wm = w >> 2, wn = w & 3;     // wave tile 2x4
  const int l15 = lane & 15, lhi = lane >> 4;
  const int lr8 = lane >> 3;
  const int schunk = (lane & 7) ^ lr8;   // pre-swizzled source chunk

  const int nkt = K / 64;
  const int span = nkt;                  // no diag variant here

  f32x4 acc[8][4];
  #pragma unroll
  for (int i = 0; i < 8; ++i)
    #pragma unroll
    for (int j = 0; j < 4; ++j) acc[i][j] = (f32x4)0.f;

  auto stageA = [&](int qm, int kt, int buf) {
    #pragma unroll
    for (int li = 0; li < 2; ++li) {
      int u = li * 8 + w;
      int h = u >> 3;
      int rl = qm * 64 + (u & 7) * 8;
      gload16(A + (size_t)(m0 + h * 128 + rl + lr8) * lda + (size_t)(kt * 64 + schunk * 8),
              &lds2[buf * 32768 + h * 8192 + rl * 64]);
    }
  };
  auto stageB = [&](int qn, int kt, int buf) {
    #pragma unroll
    for (int li = 0; li < 2; ++li) {
      int u = li * 8 + w;
      int h = u >> 3, sub = (u >> 2) & 1;
      int rl = qn * 32 + sub * 64 + (u & 3) * 8;
      gload16(B + (size_t)(n0 + h * 128 + rl + lr8) * ldb + (size_t)(kt * 64 + schunk * 8),
              &lds2[buf * 32768 + 16384 + h * 8192 + rl * 64]);
    }
  };

  bf16x8 af[4][2], bv[2][2];
  auto readA = [&](int qm, int buf) {
    const u16* base = &lds2[buf * 32768 + wm * 8192];
    #pragma unroll
    for (int mi = 0; mi < 4; ++mi) {
      int r = qm * 64 + mi * 16 + l15;
      #pragma unroll
      for (int kk = 0; kk < 2; ++kk) {
        int s = (kk * 4 + lhi) ^ (r & 7);
        af[mi][kk] = *reinterpret_cast<const bf16x8*>(&base[r * 64 + s * 8]);
      }
    }
  };
  auto readB = [&](int qn, int buf) {
    const u16* base = &lds2[buf * 32768 + 16384 + (wn >> 1) * 8192];
    #pragma unroll
    for (int ni = 0; ni < 2; ++ni) {
      int r = (wn & 1) * 64 + qn * 32 + ni * 16 + l15;
      #pragma unroll
      for (int kk = 0; kk < 2; ++kk) {
        int s = (kk * 4 + lhi) ^ (r & 7);
        bv[ni][kk] = *reinterpret_cast<const bf16x8*>(&base[r * 64 + s * 8]);
      }
    }
  };
  auto mmaq = [&](int qm, int qn) {
    __builtin_amdgcn_s_setprio(1);
    #pragma unroll
    for (int kk = 0; kk < 2; ++kk)
      #pragma unroll
      for (int mi = 0; mi < 4; ++mi)
        #pragma unroll
        for (int ni = 0; ni < 2; ++ni)
          acc[qm * 4 + mi][qn * 2 + ni] = __builtin_amdgcn_mfma_f32_16x16x32_bf16(
              af[mi][kk], bv[ni][kk], acc[qm * 4 + mi][qn * 2 + ni], 0, 0, 0);
    __builtin_amdgcn_s_setprio(0);
  };

  // prologue: tile0 fully + tile1 {A-q0, B-qn1, A-q1}
  {
    int k1 = (1 < span) ? 1 : 0;
    stageA(0, 0, 0); stageB(0, 0, 0); stageA(1, 0, 0); stageB(1, 0, 0);
    stageA(0, k1, 1); stageB(1, k1, 1); stageA(1, k1, 1);
  }
  asm volatile("s_waitcnt vmcnt(6)" ::: "memory");
  __builtin_amdgcn_s_barrier();

  for (int t = 0; t < span; ++t) {
    const int buf = t & 1, nb = buf ^ 1;
    int t1 = t + 1; if (t1 >= span) t1 -= span;
    int t2 = t + 2; if (t2 >= span) t2 -= span;

    // phase 0: quadrant (0,0)
    readA(0, buf); readB(0, buf);
    stageB(0, t1, nb);
    __builtin_amdgcn_s_barrier();
    mmaq(0, 0);
    __builtin_amdgcn_s_barrier();

    // phase 1: quadrant (0,1)
    readB(1, buf);
    stageA(0, t2, buf);
    __builtin_amdgcn_s_barrier();
    mmaq(0, 1);
    __builtin_amdgcn_s_barrier();

    // phase 2: quadrant (1,1)
    readA(1, buf);
    stageB(1, t2, buf);
    __builtin_amdgcn_s_barrier();
    mmaq(1, 1);
    __builtin_amdgcn_s_barrier();

    // phase 3: quadrant (1,0)
    readB(0, buf);
    stageA(1, t2, buf);
    __builtin_amdgcn_s_barrier();
    mmaq(1, 0);
    asm volatile("s_waitcnt vmcnt(6)" ::: "memory");
    __builtin_amdgcn_s_barrier();
  }

  // epilogue
  if (EPI == 0) {
    u16* C = (u16*)Cv + (size_t)batch * cbs_;
    #pragma unroll
    for (int a = 0; a < 8; ++a) {
      int ro = (a >> 2) * 64 + (a & 3) * 16;
      #pragma unroll
      for (int q = 0; q < 4; ++q) {
        int row = m0 + wm * 128 + ro + lhi * 4 + q;
        u16* crow = C + (size_t)row * ldc + n0 + wn * 64 + l15;
        #pragma unroll
        for (int ni = 0; ni < 4; ++ni) crow[ni * 16] = f2bf(acc[a][ni][q]);
      }
    }
  } else {
    u16* C = (u16*)Cv + (size_t)batch * cbs_;
    const float* ldp = ldec + (size_t)batch * ld_stride;
    float ldv[4];
    #pragma unroll
    for (int ni = 0; ni < 4; ++ni) ldv[ni] = ldp[n0 + wn * 64 + ni * 16 + l15];
    const float sc = 0.03125f;   // 1/sqrt(1024)
    #pragma unroll
    for (int a = 0; a < 8; ++a) {
      int ro = (a >> 2) * 64 + (a & 3) * 16;
      #pragma unroll
      for (int q = 0; q < 4; ++q) {
        int row = m0 + wm * 128 + ro + lhi * 4 + q;
        u16* crow = C + (size_t)row * ldc + n0 + wn * 64 + l15;
        #pragma unroll
        for (int ni = 0; ni < 4; ++ni) {
          int col = n0 + wn * 64 + ni * 16 + l15;
          int d = col - row;
          float wgt = (d > 0) ? expf(ldv[ni] * (float)(d - 1)) : 0.f;
          crow[ni * 16] = f2bf(acc[a][ni][q] * sc * wgt);
        }
      }
    }
  }
  asm volatile("s_waitcnt vmcnt(0)" ::: "memory");  // drain tail prefetches
}

// ---------- 256x128 minimum-2-phase GEMM ----------
// 8 waves (4M x 2N), per-wave 64x64 out, BK=64, 2x48KB LDS dbuf.
// Loop: stage(t+1 -> other buf) ; read frags(t) ; 32 MFMA ; vmcnt(0) ; barrier.
template <int EPI>   // 0: bf16 store, 2: fp32 * scale
__global__ __launch_bounds__(512, 2)
void gemm256n(const u16* __restrict__ Ab, const u16* __restrict__ Bb,
              void* __restrict__ Cv, int lda, int ldb, int ldc, int K,
              int tiles_n, int diag, const float* __restrict__ scale_ptr,
              long long abs_, long long bbs_, long long cbs_) {
  __shared__ __align__(16) u16 lds2[49152];   // 96 KiB: 2 x (A 32KB | B 16KB)

  const int batch = blockIdx.y;
  const u16* A = Ab + (size_t)batch * abs_;
  const u16* B = Bb + (size_t)batch * bbs_;

  const int it = blockIdx.x / tiles_n;
  const int jt = blockIdx.x % tiles_n;
  const int m0 = it * 256, n0 = jt * 128;

  const int tid = threadIdx.x;
  const int lane = tid & 63;
  const int w = tid >> 6;
  const int wm = w >> 1, wn = w & 1;     // wave tile 4x2, wave = 64x64
  const int l15 = lane & 15, lhi = lane >> 4;
  const int lr8 = lane >> 3;
  const int schunk = (lane & 7) ^ lr8;

  const int kt0 = diag ? it * 4 : 0;
  const int nkt = K / 64;
  const int span = nkt - kt0;

  f32x4 acc[4][4];
  #pragma unroll
  for (int i = 0; i < 4; ++i)
    #pragma unroll
    for (int j = 0; j < 4; ++j) acc[i][j] = (f32x4)0.f;

  auto stage = [&](int kt, int buf) {
    #pragma unroll
    for (int u = 0; u < 4; ++u) {
      int row = u * 64 + w * 8 + lr8;
      gload16(A + (size_t)(m0 + row) * lda + (size_t)(kt * 64 + schunk * 8),
              &lds2[buf * 24576 + (u * 64 + w * 8) * 64]);
    }
    #pragma unroll
    for (int u = 0; u < 2; ++u) {
      int row = u * 64 + w * 8 + lr8;
      gload16(B + (size_t)(n0 + row) * ldb + (size_t)(kt * 64 + schunk * 8),
              &lds2[buf * 24576 + 16384 + (u * 64 + w * 8) * 64]);
    }
  };

  // prologue
  stage(kt0, 0);
  asm volatile("s_waitcnt vmcnt(0)" ::: "memory");
  __builtin_amdgcn_s_barrier();

  for (int t = 0; t < span; ++t) {
    const int buf = t & 1, nb = buf ^ 1;
    int t1 = t + 1; if (t1 >= span) t1 = 0;
    stage(kt0 + t1, nb);

    bf16x8 af[4][2], bv[4][2];
    const u16* baseA = &lds2[buf * 24576];
    const u16* baseB = &lds2[buf * 24576 + 16384];
    #pragma unroll
    for (int mi = 0; mi < 4; ++mi) {
      int r = wm * 64 + mi * 16 + l15;
      #pragma unroll
      for (int kk = 0; kk < 2; ++kk) {
        int s = (kk * 4 + lhi) ^ (r & 7);
        af[mi][kk] = *reinterpret_cast<const bf16x8*>(&baseA[r * 64 + s * 8]);
      }
    }
    #pragma unroll
    for (int ni = 0; ni < 4; ++ni) {
      int r = wn * 64 + ni * 16 + l15;
      #pragma unroll
      for (int kk = 0; kk < 2; ++kk) {
        int s = (kk * 4 + lhi) ^ (r & 7);
        bv[ni][kk] = *reinterpret_cast<const bf16x8*>(&baseB[r * 64 + s * 8]);
      }
    }
    __builtin_amdgcn_s_setprio(1);
    #pragma unroll
    for (int kk = 0; kk < 2; ++kk)
      #pragma unroll
      for (int mi = 0; mi < 4; ++mi)
        #pragma unroll
        for (int ni = 0; ni < 4; ++ni)
          acc[mi][ni] = __builtin_amdgcn_mfma_f32_16x16x32_bf16(
              af[mi][kk], bv[ni][kk], acc[mi][ni], 0, 0, 0);
    __builtin_amdgcn_s_setprio(0);
    asm volatile("s_waitcnt vmcnt(0)" ::: "memory");
    __builtin_amdgcn_s_barrier();
  }

  // epilogue: frag (mi,ni) -> rows m0+wm*64+mi*16+lhi*4+q, col n0+wn*64+ni*16+l15
  if (EPI == 0) {
    u16* C = (u16*)Cv + (size_t)batch * cbs_;
    #pragma unroll
    for (int mi = 0; mi < 4; ++mi)
      #pragma unroll
      for (int q = 0; q < 4; ++q) {
        int row = m0 + wm * 64 + mi * 16 + lhi * 4 + q;
        u16* crow = C + (size_t)row * ldc + n0 + wn * 64 + l15;
        #pragma unroll
        for (int ni = 0; ni < 4; ++ni) crow[ni * 16] = f2bf(acc[mi][ni][q]);
      }
  } else {
    float* C = (float*)Cv + (size_t)batch * cbs_;
    const float sc = scale_ptr[0];
    #pragma unroll
    for (int mi = 0; mi < 4; ++mi)
      #pragma unroll
      for (int q = 0; q < 4; ++q) {
        int row = m0 + wm * 64 + mi * 16 + lhi * 4 + q;
        float* crow = C + (size_t)row * ldc + n0 + wn * 64 + l15;
        #pragma unroll
        for (int ni = 0; ni < 4; ++ni) crow[ni * 16] = acc[mi][ni][q] * sc;
      }
  }
}

extern "C" void kernel_launch(void* const* d_in, const int* in_sizes, int n_in,
                              void* d_out, int out_size, void* d_ws, size_t ws_size,
                              hipStream_t stream) {
  const float* x   = (const float*)d_in[0];
  const float* Wq  = (const float*)d_in[1];
  const float* Wk  = (const float*)d_in[2];
  const float* Wv  = (const float*)d_in[3];
  const float* Wo  = (const float*)d_in[4];
  const float* Wd  = (const float*)d_in[5];
  const float* bd  = (const float*)d_in[6];
  const float* osc = (const float*)d_in[7];
  float* out = (float*)d_out;

  char* ws = (char*)d_ws;
  size_t off = 0;
  u16* Xbf  = (u16*)(ws + off); off += (size_t)8192 * 1024 * 2;
  u16* Wall = (u16*)(ws + off); off += (size_t)4096 * 1024 * 2;
  u16* VT   = (u16*)(ws + off); off += (size_t)1024 * 8192 * 2;
  u16* S    = (u16*)(ws + off); off += (size_t)4 * 2048 * 2048 * 2;
  float* ldec = (float*)(ws + off); off += (size_t)8192 * 4;
  u16* QK   = (u16*)(ws + off); off += (size_t)8192 * 2048 * 2;
  u16* R    = QK;  // alias: QK dead once S built

  u16* Wqk = Wall;
  u16* Wvb = Wall + 2 * 1048576;
  u16* Wob = Wall + 3 * 1048576;

  // 1) casts + decay
  xcast_decay<<<8192, 256, 0, stream>>>(x, Xbf, Wd, bd, ldec);
  wcast<<<4096, 256, 0, stream>>>(Wq, Wk, Wv, Wo, Wall);

  // 2) QK = Xbf @ Wqk^T  [8192 x 2048]   (256 blocks)
  gemm256<0><<<dim3(32 * 8, 1), 512, 0, stream>>>(
      Xbf, Wqk, QK, 1024, 1024, 2048, 1024, 8, nullptr, 0, 0, 0, 0);

  // 3) VT = Wvb @ Xbf^T  [1024 x 8192]   (256 blocks)
  gemm256n<0><<<dim3(4 * 64, 1), 512, 0, stream>>>(
      Wvb, Xbf, VT, 1024, 1024, 8192, 1024, 64, 0, nullptr, 0, 0, 0);

  // 4) S_b = (Q_b K_b^T /32) ∘ weights -> bf16, upper-tri tiles (144 live)
  gemm256<1><<<dim3(8 * 8, 4), 512, 0, stream>>>(
      QK, QK + 1024, S, 2048, 2048, 2048, 1024, 8, ldec,
      4194304LL, 4194304LL, 4194304LL, 2048);

  // 5) R_b = S_b @ V_b  [2048 x 1024], K from diagonal   (256 blocks)
  gemm256n<0><<<dim3(8 * 8, 4), 512, 0, stream>>>(
      S, VT, R, 2048, 8192, 1024, 2048, 8, 1, nullptr,
      4194304LL, 2048LL, 2097152LL);

  // 6) out = R @ Wo^T * out_scale  [8192 x 1024] fp32   (256 blocks)
  gemm256n<2><<<dim3(32 * 8, 1), 512, 0, stream>>>(
      R, Wob, out, 1024, 1024, 1024, 1024, 8, 0, osc, 0, 0, 0);
}

// Round 4
// 177.296 us; speedup vs baseline: 1.2224x; 1.0970x over previous
//
#include <hip/hip_runtime.h>

// AdaptiveDecayMemory: out = ((Q K^T * scale) ∘ W_decay) V Wo^T * out_scale
// B=4, T=2048, D=1024.  bf16 MFMA, fp32 accum.
// Single GEMM template: 256x128 tile, 8 waves (4Mx2N, wave=64x64), BK=64,
// 3-buffer LDS rotation (144 KiB), ONE barrier + counted vmcnt(6) per K-tile.
// Stage(t+2) issued at iter t -> 2 iterations of HBM-latency cover.

using u16 = unsigned short;
typedef __bf16 bf16x8 __attribute__((ext_vector_type(8)));
typedef float f32x4 __attribute__((ext_vector_type(4)));

__device__ inline u16 f2bf(float f) {
  unsigned u = __builtin_bit_cast(unsigned, f);
  unsigned r = (u + 0x7FFFu + ((u >> 16) & 1u)) >> 16;   // RNE
  return (u16)r;
}

__device__ inline void gload16(const u16* g, u16* l) {
  __builtin_amdgcn_global_load_lds(
      (const __attribute__((address_space(1))) void*)g,
      (__attribute__((address_space(3))) void*)l, 16, 0, 0);
}

// ---------- fused x cast (fp32->bf16) + decay logit GEMV ----------
__global__ __launch_bounds__(256) void xcast_decay(const float* __restrict__ x,
    u16* __restrict__ Xbf, const float* __restrict__ Wd,
    const float* __restrict__ bd, float* __restrict__ ldec) {
  int row = blockIdx.x;
  int t = threadIdx.x;
  float4 f = reinterpret_cast<const float4*>(x + (size_t)row * 1024)[t];
  float4 g = reinterpret_cast<const float4*>(Wd)[t];
  ushort4 o;
  o.x = f2bf(f.x); o.y = f2bf(f.y); o.z = f2bf(f.z); o.w = f2bf(f.w);
  reinterpret_cast<ushort4*>(Xbf + (size_t)row * 1024)[t] = o;
  float s = f.x * g.x + f.y * g.y + f.z * g.z + f.w * g.w;
  #pragma unroll
  for (int off = 32; off > 0; off >>= 1) s += __shfl_xor(s, off);
  __shared__ float red[4];
  if ((t & 63) == 0) red[t >> 6] = s;
  __syncthreads();
  if (t == 0) {
    float tot = red[0] + red[1] + red[2] + red[3];
    float dec = 1.f / (1.f + expf(-(tot + bd[0])));
    ldec[row] = logf(dec + 1e-8f);
  }
}

// ---------- weight cast: [Wq;Wk;Wv;Wo] -> Wall ----------
__global__ __launch_bounds__(256) void wcast(const float* __restrict__ Wq,
    const float* __restrict__ Wk, const float* __restrict__ Wv,
    const float* __restrict__ Wo, u16* __restrict__ Wall) {
  int b = blockIdx.x;
  int m = b >> 10;
  const float* src = (m == 0) ? Wq : (m == 1) ? Wk : (m == 2) ? Wv : Wo;
  int i = ((b & 1023) * 256 + threadIdx.x) * 4;
  float4 f = *reinterpret_cast<const float4*>(src + i);
  ushort4 o;
  o.x = f2bf(f.x); o.y = f2bf(f.y); o.z = f2bf(f.z); o.w = f2bf(f.w);
  *reinterpret_cast<ushort4*>(Wall + (size_t)m * 1048576 + i) = o;
}

// ---------- 256x128, 3-buffer, counted-vmcnt GEMM ----------
// C[m,n] = sum_k A[m,k]*B[n,k]  (both K-contiguous).
// EPI 0: bf16 store.  EPI 1: decay epilogue -> bf16 (skip jt<2*it tiles).
// EPI 2: fp32 * scale_ptr[0].
// diag=1: K-loop starts at K-tile it*4 (retrieval GEMM over upper-tri S).
// Per K-tile per thread: exactly 6 global_load_lds (4 A + 2 B) -> vmcnt units.
template <int EPI>
__global__ __launch_bounds__(512, 2)
void gemm3(const u16* __restrict__ Ab, const u16* __restrict__ Bb,
           void* __restrict__ Cv, int lda, int ldb, int ldc, int K,
           int tiles_n, int diag, const float* __restrict__ ldec,
           const float* __restrict__ scale_ptr,
           long long abs_, long long bbs_, long long cbs_, int ld_stride) {
  __shared__ __align__(16) u16 lds2[73728];   // 3 x (A 32KB | B 16KB) = 144 KiB

  const int batch = blockIdx.y;
  const u16* A = Ab + (size_t)batch * abs_;
  const u16* B = Bb + (size_t)batch * bbs_;

  const int it = blockIdx.x / tiles_n;
  const int jt = blockIdx.x % tiles_n;
  if (EPI == 1 && jt < 2 * it) return;   // all-zero anti-causal tiles, never read
  const int m0 = it * 256, n0 = jt * 128;

  const int tid = threadIdx.x;
  const int lane = tid & 63;
  const int w = tid >> 6;
  const int wm = w >> 1, wn = w & 1;     // wave = 64x64 of the 256x128 tile
  const int l15 = lane & 15, lhi = lane >> 4;
  const int lr8 = lane >> 3;
  const int schunk = (lane & 7) ^ lr8;   // pre-swizzled source chunk (rule #21)

  const int kt0 = diag ? it * 4 : 0;
  const int nkt = K / 64;
  const int span = nkt - kt0;            // >= 4 in all uses

  f32x4 acc[4][4];
  #pragma unroll
  for (int i = 0; i < 4; ++i)
    #pragma unroll
    for (int j = 0; j < 4; ++j) acc[i][j] = (f32x4)0.f;

  auto stage = [&](int kt, int buf) {
    const size_t kb = (size_t)kt * 64 + schunk * 8;
    u16* lb = &lds2[buf * 24576];
    #pragma unroll
    for (int u = 0; u < 4; ++u)
      gload16(A + (size_t)(m0 + u * 64 + w * 8 + lr8) * lda + kb,
              lb + (u * 64 + w * 8) * 64);
    #pragma unroll
    for (int u = 0; u < 2; ++u)
      gload16(B + (size_t)(n0 + u * 64 + w * 8 + lr8) * ldb + kb,
              lb + 16384 + (u * 64 + w * 8) * 64);
  };

  // prologue: tiles 0,1 into bufs 0,1; drain tile 0 only (6 = tile1 in flight)
  stage(kt0, 0);
  stage(kt0 + 1, 1);
  asm volatile("s_waitcnt vmcnt(6)" ::: "memory");
  __builtin_amdgcn_s_barrier();

  int bR = 0, bS = 2;
  for (int t = 0; t < span; ++t) {
    const u16* baseA = &lds2[bR * 24576];
    const u16* baseB = baseA + 16384;

    bf16x8 af[4][2], bv[4][2];
    #pragma unroll
    for (int mi = 0; mi < 4; ++mi) {
      int r = wm * 64 + mi * 16 + l15;
      #pragma unroll
      for (int kk = 0; kk < 2; ++kk) {
        int s = (kk * 4 + lhi) ^ (r & 7);
        af[mi][kk] = *reinterpret_cast<const bf16x8*>(&baseA[r * 64 + s * 8]);
      }
    }
    #pragma unroll
    for (int ni = 0; ni < 4; ++ni) {
      int r = wn * 64 + ni * 16 + l15;
      #pragma unroll
      for (int kk = 0; kk < 2; ++kk) {
        int s = (kk * 4 + lhi) ^ (r & 7);
        bv[ni][kk] = *reinterpret_cast<const bf16x8*>(&baseB[r * 64 + s * 8]);
      }
    }

    // prefetch tile t+2 into the buffer last read at iter t-1 (barrier-fenced)
    int t2 = t + 2; if (t2 >= span) t2 = span - 1;   // tail: redundant refetch
    stage(kt0 + t2, bS);

    __builtin_amdgcn_s_setprio(1);
    #pragma unroll
    for (int kk = 0; kk < 2; ++kk)
      #pragma unroll
      for (int mi = 0; mi < 4; ++mi)
        #pragma unroll
        for (int ni = 0; ni < 4; ++ni)
          acc[mi][ni] = __builtin_amdgcn_mfma_f32_16x16x32_bf16(
              af[mi][kk], bv[ni][kk], acc[mi][ni], 0, 0, 0);
    __builtin_amdgcn_s_setprio(0);

    // drain tile t+1 (issued at iter t-1); tile t+2 (6 loads) stays in flight
    asm volatile("s_waitcnt vmcnt(6)" ::: "memory");
    __builtin_amdgcn_s_barrier();

    bR = (bR == 2) ? 0 : bR + 1;
    bS = (bS == 2) ? 0 : bS + 1;
  }
  asm volatile("s_waitcnt vmcnt(0)" ::: "memory");  // drain before exit

  // epilogue: frag (mi,ni) -> row m0+wm*64+mi*16+lhi*4+q, col n0+wn*64+ni*16+l15
  if (EPI == 0) {
    u16* C = (u16*)Cv + (size_t)batch * cbs_;
    #pragma unroll
    for (int mi = 0; mi < 4; ++mi)
      #pragma unroll
      for (int q = 0; q < 4; ++q) {
        int row = m0 + wm * 64 + mi * 16 + lhi * 4 + q;
        u16* crow = C + (size_t)row * ldc + n0 + wn * 64 + l15;
        #pragma unroll
        for (int ni = 0; ni < 4; ++ni) crow[ni * 16] = f2bf(acc[mi][ni][q]);
      }
  } else if (EPI == 1) {
    u16* C = (u16*)Cv + (size_t)batch * cbs_;
    const float* ldp = ldec + (size_t)batch * ld_stride;
    float ldv[4];
    #pragma unroll
    for (int ni = 0; ni < 4; ++ni) ldv[ni] = ldp[n0 + wn * 64 + ni * 16 + l15];
    const float sc = 0.03125f;   // 1/sqrt(1024)
    #pragma unroll
    for (int mi = 0; mi < 4; ++mi)
      #pragma unroll
      for (int q = 0; q < 4; ++q) {
        int row = m0 + wm * 64 + mi * 16 + lhi * 4 + q;
        u16* crow = C + (size_t)row * ldc + n0 + wn * 64 + l15;
        #pragma unroll
        for (int ni = 0; ni < 4; ++ni) {
          int col = n0 + wn * 64 + ni * 16 + l15;
          int d = col - row;
          float wgt = (d > 0) ? expf(ldv[ni] * (float)(d - 1)) : 0.f;
          crow[ni * 16] = f2bf(acc[mi][ni][q] * sc * wgt);
        }
      }
  } else {
    float* C = (float*)Cv + (size_t)batch * cbs_;
    const float sc = scale_ptr[0];
    #pragma unroll
    for (int mi = 0; mi < 4; ++mi)
      #pragma unroll
      for (int q = 0; q < 4; ++q) {
        int row = m0 + wm * 64 + mi * 16 + lhi * 4 + q;
        float* crow = C + (size_t)row * ldc + n0 + wn * 64 + l15;
        #pragma unroll
        for (int ni = 0; ni < 4; ++ni) crow[ni * 16] = acc[mi][ni][q] * sc;
      }
  }
}

extern "C" void kernel_launch(void* const* d_in, const int* in_sizes, int n_in,
                              void* d_out, int out_size, void* d_ws, size_t ws_size,
                              hipStream_t stream) {
  const float* x   = (const float*)d_in[0];
  const float* Wq  = (const float*)d_in[1];
  const float* Wk  = (const float*)d_in[2];
  const float* Wv  = (const float*)d_in[3];
  const float* Wo  = (const float*)d_in[4];
  const float* Wd  = (const float*)d_in[5];
  const float* bd  = (const float*)d_in[6];
  const float* osc = (const float*)d_in[7];
  float* out = (float*)d_out;

  char* ws = (char*)d_ws;
  size_t off = 0;
  u16* Xbf  = (u16*)(ws + off); off += (size_t)8192 * 1024 * 2;
  u16* Wall = (u16*)(ws + off); off += (size_t)4096 * 1024 * 2;
  u16* VT   = (u16*)(ws + off); off += (size_t)1024 * 8192 * 2;
  u16* S    = (u16*)(ws + off); off += (size_t)4 * 2048 * 2048 * 2;
  float* ldec = (float*)(ws + off); off += (size_t)8192 * 4;
  u16* QK   = (u16*)(ws + off); off += (size_t)8192 * 2048 * 2;
  u16* R    = QK;  // alias: QK dead once S built

  u16* Wqk = Wall;
  u16* Wvb = Wall + 2 * 1048576;
  u16* Wob = Wall + 3 * 1048576;

  // 1) casts + decay
  xcast_decay<<<8192, 256, 0, stream>>>(x, Xbf, Wd, bd, ldec);
  wcast<<<4096, 256, 0, stream>>>(Wq, Wk, Wv, Wo, Wall);

  // 2) QK = Xbf @ Wqk^T  [8192 x 2048]   (512 blocks = 2 clean passes)
  gemm3<0><<<dim3(32 * 16, 1), 512, 0, stream>>>(
      Xbf, Wqk, QK, 1024, 1024, 2048, 1024, 16, 0, nullptr, nullptr, 0, 0, 0, 0);

  // 3) VT = Wvb @ Xbf^T  [1024 x 8192]   (256 blocks)
  gemm3<0><<<dim3(4 * 64, 1), 512, 0, stream>>>(
      Wvb, Xbf, VT, 1024, 1024, 8192, 1024, 64, 0, nullptr, nullptr, 0, 0, 0, 0);

  // 4) S_b = (Q_b K_b^T /32) ∘ weights -> bf16  (288 live blocks of 512)
  gemm3<1><<<dim3(8 * 16, 4), 512, 0, stream>>>(
      QK, QK + 1024, S, 2048, 2048, 2048, 1024, 16, 0, ldec, nullptr,
      4194304LL, 4194304LL, 4194304LL, 2048);

  // 5) R_b = S_b @ V_b  [2048 x 1024], K-loop from diagonal  (256 blocks)
  gemm3<0><<<dim3(8 * 8, 4), 512, 0, stream>>>(
      S, VT, R, 2048, 8192, 1024, 2048, 8, 1, nullptr, nullptr,
      4194304LL, 2048LL, 2097152LL, 0);

  // 6) out = R @ Wo^T * out_scale  [8192 x 1024] fp32  (256 blocks)
  gemm3<2><<<dim3(32 * 8, 1), 512, 0, stream>>>(
      R, Wob, out, 1024, 1024, 1024, 1024, 8, 0, nullptr, osc, 0, 0, 0, 0);
}